// Round 4
// baseline (650.135 us; speedup 1.0000x reference)
//
#include <hip/hip_runtime.h>
#include <math.h>

// Problem constants (setup_inputs: N=32, C=1, W=512, L=512)
#define WD 512          // image / detector width
#define PF 1024         // FFT pad length
#define LH2 1028        // shifted ramp-kernel table length

// Workspace layout (float offsets). ws bytes: 16 KB + 33.55 MB table.
#define OFF_H2 0        // 1028 floats
#define OFF_ANG 2048    // 512 x float4 (chw, shw, wB, iA-bits)
#define OFF_PK 4096     // packed fp16 sinogram: [g][l][s] uint4 (4 imgs x (y[s],y[s+1]))

typedef __fp16 half2_t __attribute__((ext_vector_type(2)));

__device__ __forceinline__ half2_t pkh(float a, float b) {
  return __builtin_amdgcn_cvt_pkrtz(a, b);   // v_cvt_pkrtz_f16_f32
}
__device__ __forceinline__ unsigned pkbits(float a, float b) {
  return __builtin_bit_cast(unsigned, pkh(a, b));
}
__device__ __forceinline__ float dot2f(unsigned tapbits, half2_t w, float c) {
  half2_t tp = __builtin_bit_cast(half2_t, tapbits);
  return __builtin_amdgcn_fdot2(tp, w, c, false);   // v_dot2_f32_f16
}
// Bank swizzle: stride-8/16-float lanes -> stride 9/18 mod 32 (<=2-way = free).
__device__ __forceinline__ int hsw(int i) { return i + (i >> 3); }

__device__ __forceinline__ float t2(int p) {
  return (float)(-1.0 + 2.0 * (double)p / (double)(WD - 1));
}

// Async global->LDS, 16 B per lane. HW semantics (m104): LDS dest is
// wave-uniform base + lane*16; global src is per-lane.
__device__ __forceinline__ void gload_lds16(const void* g, void* l) {
  __builtin_amdgcn_global_load_lds(
      (const __attribute__((address_space(1))) unsigned*)g,
      (__attribute__((address_space(3))) unsigned*)l, 16, 0, 0);
}

// ---------------------------------------------------------------------------
// Setup: h2[i] = h[(i-512) & 1023] via v_cos (arg in REVOLUTIONS).
// h has EXACT zeros at all even offsets d != 0 (triangle spectrum 2|f|
// frequency-sampled with even P). filter_kernel consumes only the odd taps +
// the d=0 center tap; the table stays full-length so the compressed view
// h2[2t+1] / h2[512] can be loaded from it.
// ---------------------------------------------------------------------------
__global__ void setup_kernel(const float* __restrict__ theta,
                             float* __restrict__ ws, int L) {
  int gid = blockIdx.x * blockDim.x + threadIdx.x;
  if (gid < LH2) {
    int dd = gid - (PF / 2);
    if (dd < 0) dd = -dd;
    float acc = 0.f;
    for (int k = 0; k < PF; ++k) {
      int kk = (k <= PF / 2) ? k : (PF - k);
      float filt = 2.f * (float)kk * (1.f / (float)PF);
      int m = (k * dd) & (PF - 1);            // phase in [0,1) revolutions
#if __has_builtin(__builtin_amdgcn_cosf)
      float cv = __builtin_amdgcn_cosf((float)m * (1.f / (float)PF));
#else
      float cv = cosf((float)m * (6.28318530717958647692f / (float)PF));
#endif
      acc = fmaf(filt, cv, acc);
    }
    ws[OFF_H2 + gid] = acc * (1.f / (float)PF);
  } else if (gid < LH2 + L) {
    int l = gid - LH2;
    double rad = (double)theta[l] * 0.017453292519943295;
    const float hw = 0.5f * (float)(WD - 1);
    float cx = (float)l * (float)((double)(WD - 1) / (double)(L - 1));
    float c0 = floorf(cx);
    float wc = cx - c0;
    int ia = (int)c0;
    float ok = (ia + 1 <= WD - 1) ? 1.f : 0.f;
    float4 a;
    a.x = (float)cos(rad) * hw;
    a.y = (float)sin(rad) * hw;
    a.z = wc * ok;                       // wB (0 when L==WD: cx = l exactly)
    a.w = __int_as_float(ia);
    ((float4*)(ws + OFF_ANG))[l] = a;
  }
}

// ---------------------------------------------------------------------------
// Ramp filter -> packed fp16 table. v2: odd-taps-only convolution.
// out[s] = h0*x[s] + sum_{odd d} h[d]*x[s-d]. m processed in PAIRS with a
// 9-wide rolling window over the compressed odd-tap table ho[t] = h2[2t+1].
// FMAs per thread: 8192. 256 threads, 16 l x 512 r, 2x16 microtile, 4 blk/CU.
// ---------------------------------------------------------------------------
__global__ __launch_bounds__(256, 4) void filter_kernel(
    const float* __restrict__ x, const float* __restrict__ ws,
    unsigned char* __restrict__ pk) {
  __shared__ float hol[584];                    // odd taps, swizzled, +2 front guard
  __shared__ __align__(16) float bxl[64][20];   // [m][l], 16 l + 4 pad
  const int t = threadIdx.x;
  const int tx = t & 31, ty = t >> 5;          // tx: r/16 (0..31), ty: l/2 (0..7)
  const int n = blockIdx.y;
  const int g = n >> 2, k = n & 3;
  const int l0 = blockIdx.x << 4;

  for (int i = t; i < 512; i += 256) hol[2 + hsw(i)] = ws[OFF_H2 + 2 * i + 1];
  const float h0 = ws[OFF_H2 + 512];           // center tap (broadcast load)

  float acc[2][16] = {};
  const float* __restrict__ xn = x + (size_t)n * WD * WD;
  const int first = tx << 4;
  const int cchunk = first & ~63;              // chunk holding rows first..first+15

  for (int mc = 0; mc < WD; mc += 64) {
    __syncthreads();
    {                                          // stage x[mc..mc+63][l0..l0+15]
      int row = t >> 2;
      int c4 = (t & 3) << 2;
      float4 v = *(const float4*)(xn + (size_t)(mc + row) * WD + l0 + c4);
      *(float4*)(&bxl[row][c4]) = v;
    }
    __syncthreads();
    const int tb = (first + 512 - mc) >> 1;    // rbase/2 (rbase always even)
    float w[9];
#pragma unroll
    for (int j = 0; j < 9; ++j) w[j] = hol[2 + hsw(tb - 1 + j)];
    if (mc == cchunk) {                        // center tap h0 * x[s]
      const int rloc = first & 63;
#pragma unroll
      for (int j = 0; j < 16; ++j) {
        float2 cv = *(const float2*)(&bxl[rloc + j][ty << 1]);
        acc[0][j] = fmaf(h0, cv.x, acc[0][j]);
        acc[1][j] = fmaf(h0, cv.y, acc[1][j]);
      }
    }
    for (int mb = 0; mb < 64; mb += 8) {       // 4 m-pairs per batch
      float nh4[4];
      float2 bv8[8];
#pragma unroll
      for (int kk = 0; kk < 8; ++kk)           // batch LDS loads (indep)
        bv8[kk] = *(const float2*)(&bxl[mb + kk][ty << 1]);
#pragma unroll
      for (int kk = 0; kk < 4; ++kk)
        nh4[kk] = hol[2 + hsw(tb - (mb >> 1) - kk - 2)];  // hsw(-1)+2 == 0: safe
#pragma unroll
      for (int kk = 0; kk < 4; ++kk) {
        float2 xe = bv8[2 * kk], xo = bv8[2 * kk + 1];
#pragma unroll
        for (int b = 0; b < 8; ++b) {
          acc[0][2 * b + 1] = fmaf(xe.x, w[b + 1], acc[0][2 * b + 1]);
          acc[1][2 * b + 1] = fmaf(xe.y, w[b + 1], acc[1][2 * b + 1]);
          acc[0][2 * b]     = fmaf(xo.x, w[b],     acc[0][2 * b]);
          acc[1][2 * b]     = fmaf(xo.y, w[b],     acc[1][2 * b]);
        }
#pragma unroll
        for (int j = 8; j > 0; --j) w[j] = w[j - 1];   // renamed by unroll
        w[0] = nh4[kk];
      }
    }
  }

  // Epilogue: scatter into interleaved pk table (byte lane k, group g).
#pragma unroll
  for (int li = 0; li < 2; ++li) {
    int l = l0 + (ty << 1) + li;
    size_t rowb = ((size_t)(g * 512 + l) * 512) * 16 + (size_t)(k << 2);
#pragma unroll
    for (int j = 0; j < 15; ++j) {             // full entries s = first..first+14
      unsigned d = pkbits(acc[li][j], acc[li][j + 1]);
      *(unsigned*)(pk + rowb + (size_t)(first + j) * 16) = d;
    }
    unsigned lastp = pkbits(acc[li][15], 0.f);
    if (first + 15 == 511) {
      *(unsigned*)(pk + rowb + (size_t)511 * 16) = lastp;     // hi half must be 0
    } else {
      *(unsigned short*)(pk + rowb + (size_t)(first + 15) * 16) = (unsigned short)lastp;
    }
    if (first > 0) {                            // hi half of entry s = first-1
      unsigned fh = pkbits(acc[li][0], 0.f);
      *(unsigned short*)(pk + rowb + (size_t)(first - 1) * 16 + 2) = (unsigned short)fh;
    }
  }
}

// ---------------------------------------------------------------------------
// Backprojection v9: BARRIER-FREE wave-private windows.
// Round-3 finding: DS pipe is NOT saturated (removing 11% of DS instrs
// changed nothing) — ~25% of round time was barrier/lockstep overhead paid
// 256x. v9 deletes __syncthreads entirely:
//  - wave footprint 8i x 32j -> detector span per angle = 31|cos|+7|sin|
//    <= 31.8 cells (pixel->cell steps are EXACTLY cos/sin: 2*255.5 = 511).
//  - 64-cell private window/angle = ONE global_load_lds per wave into its
//    own 1 KB LDS slice; 2-deep rotation, s_waitcnt vmcnt(1) (counted,
//    never drained), sched_barrier(0) fence after (rule: compiler has no
//    dep edge from TA-written LDS to ds_read).
//  - no guard buffers: window slot clamped to [0,63]; source cell clamped
//    to [0,511]; out-of-circle pixels produce garbage that is masked at the
//    final store (same as before). In-circle pixels provably in-window
//    (base = floor(min_ry)-1, slack 30 cells).
//  - TA-write vs ds_read hazard: all of round r's ds_reads are consumed by
//    dot2s (compiler lgkmcnt) before round r+2's gload targets that buffer;
//    TA write lands >=200cy after issue. Waves fully independent; early
//    exit for out-of-circle strips is legal (no barriers).
// v7 lesson kept: vector-memory gathers are line-serial — LDS only.
// ---------------------------------------------------------------------------
__device__ __forceinline__ int stage_wave(const unsigned char* __restrict__ gb,
                                          float4 a, float wjl, float wjh,
                                          float wil, float wih, int lane,
                                          uint4* dst) {
  float mn = 255.5f + fminf(wjl * a.x, wjh * a.x) +
             fminf(-wil * a.y, -wih * a.y);
  int base = (int)floorf(mn) - 1;
  int cs = base + lane;
  cs = cs < 0 ? 0 : (cs > 511 ? 511 : cs);    // edge clamp (dup cells harmless)
  int ia = __float_as_int(a.w);
  gload_lds16(gb + (size_t)ia * (512 * 16) + (size_t)cs * 16, dst + lane);
  return base;
}

__device__ __forceinline__ void consume_wave(const uint4* __restrict__ wb,
                                             float4 a, int base, float tiv,
                                             const float* __restrict__ tjv,
                                             float acc[4][4]) {
  float bi = fmaf(tiv, -a.y, 255.5f - (float)base);   // base folded in
#pragma unroll
  for (int dj = 0; dj < 4; ++dj) {
    float ry = fmaf(tjv[dj], a.x, bi);       // >=1 for in-circle px
    int s = (int)ry;
    float w1 = ry - (float)s;
    s = s < 0 ? 0 : (s > 63 ? 63 : s);       // OOB px masked at final store
    half2_t wpk = pkh(1.f - w1, w1);
    uint4 q = wb[s];                         // ds_read_b128: 4 images
    acc[dj][0] = dot2f(q.x, wpk, acc[dj][0]);
    acc[dj][1] = dot2f(q.y, wpk, acc[dj][1]);
    acc[dj][2] = dot2f(q.z, wpk, acc[dj][2]);
    acc[dj][3] = dot2f(q.w, wpk, acc[dj][3]);
  }
}

__global__ __launch_bounds__(1024, 8) void backproj_kernel(
    const float* __restrict__ ws, const unsigned char* __restrict__ pk,
    float* __restrict__ out, int L) {
  __shared__ __align__(16) uint4 wbuf[16][2][64];   // per-wave [parity][cell]
  const int t = threadIdx.x;
  const int lane = t & 63, w = t >> 6;
  const int jh = w & 1, ib = w >> 1;         // wave = 8 i-rows x 32 j-cols
  const int j0 = (blockIdx.x & 7) << 6;
  const int i0 = (blockIdx.x >> 3) << 6;
  const int g = blockIdx.y;
  const int n0 = g << 2;

  const int li = i0 + (ib << 3) + (lane >> 3);
  const int lj = j0 + (jh << 5) + (lane & 7);      // + 8*dj
  const float tiv = t2(li);
  float tjv[4];
#pragma unroll
  for (int a = 0; a < 4; ++a) tjv[a] = t2(lj + 8 * a);

  // Wave strip bounds (uniform): i in [ibs, ibs+7], j in [jbs, jbs+31].
  const float wil = t2(i0 + (ib << 3)), wih = t2(i0 + (ib << 3) + 7);
  const float wjl = t2(j0 + (jh << 5)), wjh = t2(j0 + (jh << 5) + 31);

  // Strip fully outside circle -> zeros, done (legal: no barriers anywhere).
  {
    float mi = (wil <= 0.f && wih >= 0.f) ? 0.f : fminf(fabsf(wil), fabsf(wih));
    float mj = (wjl <= 0.f && wjh >= 0.f) ? 0.f : fminf(fabsf(wjl), fabsf(wjh));
    if (mi * mi + mj * mj > 1.f) {
#pragma unroll
      for (int k = 0; k < 4; ++k) {
        float* ob = out + (size_t)(n0 + k) * WD * WD + (size_t)li * WD;
#pragma unroll
        for (int dj = 0; dj < 4; ++dj) ob[lj + 8 * dj] = 0.f;
      }
      return;
    }
  }

  const float4* __restrict__ angp = (const float4*)(ws + OFF_ANG);
  const unsigned char* gb = pk + (size_t)g * (512 * 512 * 16);
  uint4* wb = &wbuf[w][0][0];                // this wave's 2 x 64-cell buffers

  float acc[4][4] = {};                      // [dj][img]

  float4 aC = angp[0];
  int baseC = stage_wave(gb, aC, wjl, wjh, wil, wih, lane, wb);
  float4 aN = angp[L > 1 ? 1 : 0];
  int baseN = stage_wave(gb, aN, wjl, wjh, wil, wih, lane, wb + 64);

  for (int r = 0; r < L; ++r) {
    int nn = r + 2;
    float4 aN2 = angp[nn < L ? nn : L - 1];  // prefetched 2 ahead
    // Wait for angle r's window (r+1's load may stay in flight).
    asm volatile("s_waitcnt vmcnt(1)" ::: "memory");
    __builtin_amdgcn_sched_barrier(0);
    consume_wave(wb + ((r & 1) << 6), aC, baseC, tiv, tjv, acc);
    // Buffer (r&1) now fully consumed -> stage angle r+2 into it.
    int b2 = stage_wave(gb, aN2, wjl, wjh, wil, wih, lane, wb + ((r & 1) << 6));
    aC = aN; baseC = baseN; aN = aN2; baseN = b2;
  }

  const float scale = (float)(3.14159265358979323846 / (2.0 * (double)L));
#pragma unroll
  for (int k = 0; k < 4; ++k) {
    float* ob = out + (size_t)(n0 + k) * WD * WD + (size_t)li * WD;
#pragma unroll
    for (int dj = 0; dj < 4; ++dj) {
      float rr = tiv * tiv + tjv[dj] * tjv[dj];
      ob[lj + 8 * dj] = (rr <= 1.f) ? acc[dj][k] * scale : 0.f;
    }
  }
}

extern "C" void kernel_launch(void* const* d_in, const int* in_sizes, int n_in,
                              void* d_out, int out_size, void* d_ws, size_t ws_size,
                              hipStream_t stream) {
  const float* x = (const float*)d_in[0];
  const float* theta = (const float*)d_in[1];
  float* out = (float*)d_out;
  float* ws = (float*)d_ws;
  int L = in_sizes[1];                       // 512
  int NC = in_sizes[0] / (WD * WD);          // 32
  unsigned char* pk = (unsigned char*)(ws + OFF_PK);

  int nset = LH2 + L;
  hipLaunchKernelGGL(setup_kernel, dim3((nset + 255) / 256), dim3(256), 0, stream,
                     theta, ws, L);
  hipLaunchKernelGGL(filter_kernel, dim3(32, NC), dim3(256), 0, stream,
                     x, ws, pk);
  hipLaunchKernelGGL(backproj_kernel, dim3(64, NC / 4), dim3(1024), 0, stream,
                     ws, pk, out, L);
}

// Round 5
// 587.034 us; speedup vs baseline: 1.1075x; 1.1075x over previous
//
#include <hip/hip_runtime.h>
#include <math.h>

// Problem constants (setup_inputs: N=32, C=1, W=512, L=512)
#define WD 512          // image / detector width
#define PF 1024         // FFT pad length
#define LH2 1028        // shifted ramp-kernel table length

// Workspace layout (float offsets). ws bytes: 16 KB + 33.55 MB table.
#define OFF_H2 0        // 1028 floats
#define OFF_ANG 2048    // 512 x float4 (chw, shw, wB, iA-bits)
#define OFF_PK 4096     // packed fp16 sinogram: [g][l][s] uint4 (4 imgs x (y[s],y[s+1]))

typedef __fp16 half2_t __attribute__((ext_vector_type(2)));

__device__ __forceinline__ half2_t pkh(float a, float b) {
  return __builtin_amdgcn_cvt_pkrtz(a, b);   // v_cvt_pkrtz_f16_f32
}
__device__ __forceinline__ unsigned pkbits(float a, float b) {
  return __builtin_bit_cast(unsigned, pkh(a, b));
}
__device__ __forceinline__ float dot2f(unsigned tapbits, half2_t w, float c) {
  half2_t tp = __builtin_bit_cast(half2_t, tapbits);
  return __builtin_amdgcn_fdot2(tp, w, c, false);   // v_dot2_f32_f16
}
// Bank swizzle: stride-8/16-float lanes -> stride 9/18 mod 32 (<=2-way = free).
__device__ __forceinline__ int hsw(int i) { return i + (i >> 3); }

__device__ __forceinline__ float t2(int p) {
  return (float)(-1.0 + 2.0 * (double)p / (double)(WD - 1));
}

// Async global->LDS, 16 B per lane. HW: LDS dest = wave-uniform base +
// lane*16 (per-lane dest pointer's readfirstlane must equal lane0's slot —
// our sA = t&511 layout satisfies this; validated by R3/R4 passing runs).
__device__ __forceinline__ void gload_lds16(const void* g, void* l) {
  __builtin_amdgcn_global_load_lds(
      (const __attribute__((address_space(1))) unsigned*)g,
      (__attribute__((address_space(3))) unsigned*)l, 16, 0, 0);
}

// ---------------------------------------------------------------------------
// Setup: h2[i] = h[(i-512) & 1023] via v_cos (arg in REVOLUTIONS).
// h has EXACT zeros at all even offsets d != 0 (triangle spectrum 2|f|
// frequency-sampled with even P). filter_kernel consumes only the odd taps +
// the d=0 center tap; the table stays full-length so the compressed view
// h2[2t+1] / h2[512] can be loaded from it.
// ---------------------------------------------------------------------------
__global__ void setup_kernel(const float* __restrict__ theta,
                             float* __restrict__ ws, int L) {
  int gid = blockIdx.x * blockDim.x + threadIdx.x;
  if (gid < LH2) {
    int dd = gid - (PF / 2);
    if (dd < 0) dd = -dd;
    float acc = 0.f;
    for (int k = 0; k < PF; ++k) {
      int kk = (k <= PF / 2) ? k : (PF - k);
      float filt = 2.f * (float)kk * (1.f / (float)PF);
      int m = (k * dd) & (PF - 1);            // phase in [0,1) revolutions
#if __has_builtin(__builtin_amdgcn_cosf)
      float cv = __builtin_amdgcn_cosf((float)m * (1.f / (float)PF));
#else
      float cv = cosf((float)m * (6.28318530717958647692f / (float)PF));
#endif
      acc = fmaf(filt, cv, acc);
    }
    ws[OFF_H2 + gid] = acc * (1.f / (float)PF);
  } else if (gid < LH2 + L) {
    int l = gid - LH2;
    double rad = (double)theta[l] * 0.017453292519943295;
    const float hw = 0.5f * (float)(WD - 1);
    float cx = (float)l * (float)((double)(WD - 1) / (double)(L - 1));
    float c0 = floorf(cx);
    float wc = cx - c0;
    int ia = (int)c0;
    float ok = (ia + 1 <= WD - 1) ? 1.f : 0.f;
    float4 a;
    a.x = (float)cos(rad) * hw;
    a.y = (float)sin(rad) * hw;
    a.z = wc * ok;                       // wB (0 when L==WD: cx = l exactly)
    a.w = __int_as_float(ia);
    ((float4*)(ws + OFF_ANG))[l] = a;
  }
}

// ---------------------------------------------------------------------------
// Ramp filter -> packed fp16 table. v2: odd-taps-only convolution.
// out[s] = h0*x[s] + sum_{odd d} h[d]*x[s-d]. m processed in PAIRS with a
// 9-wide rolling window over the compressed odd-tap table ho[t] = h2[2t+1].
// FMAs per thread: 8192. 256 threads, 16 l x 512 r, 2x16 microtile, 4 blk/CU.
// ---------------------------------------------------------------------------
__global__ __launch_bounds__(256, 4) void filter_kernel(
    const float* __restrict__ x, const float* __restrict__ ws,
    unsigned char* __restrict__ pk) {
  __shared__ float hol[584];                    // odd taps, swizzled, +2 front guard
  __shared__ __align__(16) float bxl[64][20];   // [m][l], 16 l + 4 pad
  const int t = threadIdx.x;
  const int tx = t & 31, ty = t >> 5;          // tx: r/16 (0..31), ty: l/2 (0..7)
  const int n = blockIdx.y;
  const int g = n >> 2, k = n & 3;
  const int l0 = blockIdx.x << 4;

  for (int i = t; i < 512; i += 256) hol[2 + hsw(i)] = ws[OFF_H2 + 2 * i + 1];
  const float h0 = ws[OFF_H2 + 512];           // center tap (broadcast load)

  float acc[2][16] = {};
  const float* __restrict__ xn = x + (size_t)n * WD * WD;
  const int first = tx << 4;
  const int cchunk = first & ~63;              // chunk holding rows first..first+15

  for (int mc = 0; mc < WD; mc += 64) {
    __syncthreads();
    {                                          // stage x[mc..mc+63][l0..l0+15]
      int row = t >> 2;
      int c4 = (t & 3) << 2;
      float4 v = *(const float4*)(xn + (size_t)(mc + row) * WD + l0 + c4);
      *(float4*)(&bxl[row][c4]) = v;
    }
    __syncthreads();
    const int tb = (first + 512 - mc) >> 1;    // rbase/2 (rbase always even)
    float w[9];
#pragma unroll
    for (int j = 0; j < 9; ++j) w[j] = hol[2 + hsw(tb - 1 + j)];
    if (mc == cchunk) {                        // center tap h0 * x[s]
      const int rloc = first & 63;
#pragma unroll
      for (int j = 0; j < 16; ++j) {
        float2 cv = *(const float2*)(&bxl[rloc + j][ty << 1]);
        acc[0][j] = fmaf(h0, cv.x, acc[0][j]);
        acc[1][j] = fmaf(h0, cv.y, acc[1][j]);
      }
    }
    for (int mb = 0; mb < 64; mb += 8) {       // 4 m-pairs per batch
      float nh4[4];
      float2 bv8[8];
#pragma unroll
      for (int kk = 0; kk < 8; ++kk)           // batch LDS loads (indep)
        bv8[kk] = *(const float2*)(&bxl[mb + kk][ty << 1]);
#pragma unroll
      for (int kk = 0; kk < 4; ++kk)
        nh4[kk] = hol[2 + hsw(tb - (mb >> 1) - kk - 2)];  // hsw(-1)+2 == 0: safe
#pragma unroll
      for (int kk = 0; kk < 4; ++kk) {
        float2 xe = bv8[2 * kk], xo = bv8[2 * kk + 1];
#pragma unroll
        for (int b = 0; b < 8; ++b) {
          acc[0][2 * b + 1] = fmaf(xe.x, w[b + 1], acc[0][2 * b + 1]);
          acc[1][2 * b + 1] = fmaf(xe.y, w[b + 1], acc[1][2 * b + 1]);
          acc[0][2 * b]     = fmaf(xo.x, w[b],     acc[0][2 * b]);
          acc[1][2 * b]     = fmaf(xo.y, w[b],     acc[1][2 * b]);
        }
#pragma unroll
        for (int j = 8; j > 0; --j) w[j] = w[j - 1];   // renamed by unroll
        w[0] = nh4[kk];
      }
    }
  }

  // Epilogue: scatter into interleaved pk table (byte lane k, group g).
#pragma unroll
  for (int li = 0; li < 2; ++li) {
    int l = l0 + (ty << 1) + li;
    size_t rowb = ((size_t)(g * 512 + l) * 512) * 16 + (size_t)(k << 2);
#pragma unroll
    for (int j = 0; j < 15; ++j) {             // full entries s = first..first+14
      unsigned d = pkbits(acc[li][j], acc[li][j + 1]);
      *(unsigned*)(pk + rowb + (size_t)(first + j) * 16) = d;
    }
    unsigned lastp = pkbits(acc[li][15], 0.f);
    if (first + 15 == 511) {
      *(unsigned*)(pk + rowb + (size_t)511 * 16) = lastp;     // hi half must be 0
    } else {
      *(unsigned short*)(pk + rowb + (size_t)(first + 15) * 16) = (unsigned short)lastp;
    }
    if (first > 0) {                            // hi half of entry s = first-1
      unsigned fh = pkbits(acc[li][0], 0.f);
      *(unsigned short*)(pk + rowb + (size_t)(first - 1) * 16 + 2) = (unsigned short)fh;
    }
  }
}

// ---------------------------------------------------------------------------
// Backprojection v10: v6 block-shared structure (R4 proved cross-wave sharing
// essential), FOUR angles per barrier round (128 barriers vs 256), guard-free
// clamped windows:
//  - buf[2][4][512] = 64 KB exactly; 2 blocks/CU kept (128 of 160 KB).
//  - staging: each thread gload_lds16's slot sA = t&511 for angles q=t>>9 and
//    q+2 of the NEXT round, issued at the top of the current round; the
//    compiler-emitted vmcnt(0) before the round-END barrier drains them —
//    a full 4-angle compute phase (~8000 cy) in flight. (R3: neutral vs
//    ds_write, fewer VALU/SGPR.)
//  - clamp instead of guards: ry = med3(ry, 0, 511); in-circle pixels have
//    ry in [0,511] exactly (entry 511 hi-half = 0 by construction); OOB
//    pixels read a valid-but-garbage cell and are masked at the final store
//    (clamp+mask correctness proven by R4's passing run). Deletes the
//    guard-zero prologue and GOFF entirely.
//  - 16 independent gathers per thread between barriers -> deeper lgkmcnt
//    pipelining across angles.
// R4 lesson: wave-private windows lose (2x traffic, latency-exposed chain).
// R1 lesson: vector-memory gathers are line-serial (~26cy) — LDS only.
// ---------------------------------------------------------------------------
__device__ __forceinline__ void accum_angle(const uint4* __restrict__ br,
                                            float chw, float shw, float tiv,
                                            const float* __restrict__ tjv,
                                            float acc[4][4]) {
  float bi = fmaf(tiv, -shw, 255.5f);
#pragma unroll
  for (int dj = 0; dj < 4; ++dj) {
    float ry = fmaf(tjv[dj], chw, bi);
    ry = fminf(fmaxf(ry, 0.f), 511.f);   // v_med3_f32; OOB px masked at store
    int s = (int)ry;
    float w1 = ry - (float)s;
    half2_t wpk = pkh(1.f - w1, w1);
    uint4 q = br[s];                     // one ds_read_b128 serves 4 images
    acc[dj][0] = dot2f(q.x, wpk, acc[dj][0]);
    acc[dj][1] = dot2f(q.y, wpk, acc[dj][1]);
    acc[dj][2] = dot2f(q.z, wpk, acc[dj][2]);
    acc[dj][3] = dot2f(q.w, wpk, acc[dj][3]);
  }
}

__global__ __launch_bounds__(1024, 8) void backproj_kernel(
    const float* __restrict__ ws, const unsigned char* __restrict__ pk,
    float* __restrict__ out, int L) {
  __shared__ __align__(16) uint4 buf[2][4][512];   // [parity][angle][cell] 64 KB
  const int t = threadIdx.x;
  const int tx = t & 15, ty = t >> 4;        // ty: 0..63 (full i of tile)
  const int j0 = (blockIdx.x & 7) << 6;
  const int i0 = (blockIdx.x >> 3) << 6;
  const int g = blockIdx.y;
  const int n0 = g << 2;

  const float tiv = t2(i0 + ty);
  float tjv[4];
#pragma unroll
  for (int a = 0; a < 4; ++a) tjv[a] = t2(j0 + tx + 16 * a);

  // Corner-tile skip: entire 64x64 tile outside the circle -> zeros, no compute.
  // (Block-uniform branch, taken before any barrier: legal.)
  {
    float il = t2(i0), ih = t2(i0 + 63);
    float jl = t2(j0), jh = t2(j0 + 63);
    float mi = (il <= 0.f && ih >= 0.f) ? 0.f : fminf(fabsf(il), fabsf(ih));
    float mj = (jl <= 0.f && jh >= 0.f) ? 0.f : fminf(fabsf(jl), fabsf(jh));
    if (mi * mi + mj * mj > 1.f) {
#pragma unroll
      for (int k = 0; k < 4; ++k) {
        float* ob = out + (size_t)(n0 + k) * WD * WD + (size_t)(i0 + ty) * WD;
#pragma unroll
        for (int dj = 0; dj < 4; ++dj) ob[j0 + tx + 16 * dj] = 0.f;
      }
      return;
    }
  }

  // Wave-strip skip (wave-uniform): 4 i-rows x 64 j-cols fully outside the
  // circle -> skip accumulation (still stage + barrier).
  bool stripOut;
  {
    int ib = i0 + (ty & ~3);
    float il = t2(ib), ih = t2(ib + 3);
    float jl = t2(j0), jh = t2(j0 + 63);
    float mi = (il <= 0.f && ih >= 0.f) ? 0.f : fminf(fabsf(il), fabsf(ih));
    float mj = (jl <= 0.f && jh >= 0.f) ? 0.f : fminf(fabsf(jl), fabsf(jh));
    stripOut = (mi * mi + mj * mj > 1.f);
  }

  const float4* __restrict__ angp = (const float4*)(ws + OFF_ANG);
  const unsigned char* gb = pk + (size_t)g * (512 * 512 * 16);

  float acc[4][4] = {};                  // [dj][img]

  const int sA = t & 511;                // staged slot
  const int q = t >> 9;                  // this thread stages angles q, q+2

  // Round-0 staging (async; drained by the barrier below).
  {
    int a0 = q, a1 = q + 2;
    int i0a = __float_as_int(angp[a0 < L ? a0 : L - 1].w);
    int i1a = __float_as_int(angp[a1 < L ? a1 : L - 1].w);
    gload_lds16(gb + (size_t)i0a * (512 * 16) + (size_t)sA * 16, &buf[0][q][sA]);
    gload_lds16(gb + (size_t)i1a * (512 * 16) + (size_t)sA * 16, &buf[0][q + 2][sA]);
  }
  __syncthreads();                       // vmcnt drained -> buf[0] ready

  const int rounds = (L + 3) >> 2;
  for (int r = 0; r < rounds; ++r) {
    const int rp = r & 1;
    if (r + 1 < rounds) {                // prefetch round r+1 into buf[rp^1]
      int nb = (r + 1) << 2;
      int a0 = nb + q, a1 = nb + q + 2;
      int i0a = __float_as_int(angp[a0 < L ? a0 : L - 1].w);
      int i1a = __float_as_int(angp[a1 < L ? a1 : L - 1].w);
      gload_lds16(gb + (size_t)i0a * (512 * 16) + (size_t)sA * 16,
                  &buf[rp ^ 1][q][sA]);
      gload_lds16(gb + (size_t)i1a * (512 * 16) + (size_t)sA * 16,
                  &buf[rp ^ 1][q + 2][sA]);
    }

    if (!stripOut) {
#pragma unroll
      for (int a = 0; a < 4; ++a) {
        int la = (r << 2) + a;
        if (la < L) {
          float4 aa = angp[la];          // uniform -> scalar loads
          accum_angle(&buf[rp][a][0], aa.x, aa.y, tiv, tjv, acc);
        }
      }
    }
    __syncthreads();                     // readers done; prefetch landed
  }

  const float scale = (float)(3.14159265358979323846 / (2.0 * (double)L));
#pragma unroll
  for (int k = 0; k < 4; ++k) {
    float* ob = out + (size_t)(n0 + k) * WD * WD + (size_t)(i0 + ty) * WD;
#pragma unroll
    for (int dj = 0; dj < 4; ++dj) {
      float rr = tiv * tiv + tjv[dj] * tjv[dj];
      ob[j0 + tx + 16 * dj] = (rr <= 1.f) ? acc[dj][k] * scale : 0.f;
    }
  }
}

extern "C" void kernel_launch(void* const* d_in, const int* in_sizes, int n_in,
                              void* d_out, int out_size, void* d_ws, size_t ws_size,
                              hipStream_t stream) {
  const float* x = (const float*)d_in[0];
  const float* theta = (const float*)d_in[1];
  float* out = (float*)d_out;
  float* ws = (float*)d_ws;
  int L = in_sizes[1];                       // 512
  int NC = in_sizes[0] / (WD * WD);          // 32
  unsigned char* pk = (unsigned char*)(ws + OFF_PK);

  int nset = LH2 + L;
  hipLaunchKernelGGL(setup_kernel, dim3((nset + 255) / 256), dim3(256), 0, stream,
                     theta, ws, L);
  hipLaunchKernelGGL(filter_kernel, dim3(32, NC), dim3(256), 0, stream,
                     x, ws, pk);
  hipLaunchKernelGGL(backproj_kernel, dim3(64, NC / 4), dim3(1024), 0, stream,
                     ws, pk, out, L);
}

// Round 7
// 497.413 us; speedup vs baseline: 1.3070x; 1.1802x over previous
//
#include <hip/hip_runtime.h>
#include <math.h>

// Problem constants (setup_inputs: N=32, C=1, W=512, L=512)
#define WD 512          // image / detector width
#define PF 1024         // FFT pad length
#define LH2 1028        // shifted ramp-kernel table length

// Workspace layout (float offsets). ws bytes: 16 KB + 33.55 MB table.
#define OFF_H2 0        // 1028 floats
#define OFF_ANG 2048    // 512 x float4 (chw, shw, wB, iA-bits)
#define OFF_PK 4096     // packed fp16 sinogram: [g][l][s] uint4 (4 imgs x (y[s],y[s+1]))

#define GOFF 107        // LDS slot = detector_index + GOFF (guards absorb out-of-circle idx)
#define GSLOTS 726      // covers idx in [-107, 618]

typedef __fp16 half2_t __attribute__((ext_vector_type(2)));
typedef _Float16 f16x8 __attribute__((ext_vector_type(8)));
typedef float f32x4v __attribute__((ext_vector_type(4)));

__device__ __forceinline__ half2_t pkh(float a, float b) {
  return __builtin_amdgcn_cvt_pkrtz(a, b);   // v_cvt_pkrtz_f16_f32
}
__device__ __forceinline__ unsigned pkbits(float a, float b) {
  return __builtin_bit_cast(unsigned, pkh(a, b));
}
__device__ __forceinline__ float dot2f(unsigned tapbits, half2_t w, float c) {
  half2_t tp = __builtin_bit_cast(half2_t, tapbits);
  return __builtin_amdgcn_fdot2(tp, w, c, false);   // v_dot2_f32_f16
}

__device__ __forceinline__ float t2(int p) {
  return (float)(-1.0 + 2.0 * (double)p / (double)(WD - 1));
}

// ---------------------------------------------------------------------------
// Setup: h2[i] = h[(i-512) & 1023] via v_cos (arg in REVOLUTIONS). UNCHANGED.
// ---------------------------------------------------------------------------
__global__ void setup_kernel(const float* __restrict__ theta,
                             float* __restrict__ ws, int L) {
  int gid = blockIdx.x * blockDim.x + threadIdx.x;
  if (gid < LH2) {
    int dd = gid - (PF / 2);
    if (dd < 0) dd = -dd;
    float acc = 0.f;
    for (int k = 0; k < PF; ++k) {
      int kk = (k <= PF / 2) ? k : (PF - k);
      float filt = 2.f * (float)kk * (1.f / (float)PF);
      int m = (k * dd) & (PF - 1);            // phase in [0,1) revolutions
#if __has_builtin(__builtin_amdgcn_cosf)
      float cv = __builtin_amdgcn_cosf((float)m * (1.f / (float)PF));
#else
      float cv = cosf((float)m * (6.28318530717958647692f / (float)PF));
#endif
      acc = fmaf(filt, cv, acc);
    }
    ws[OFF_H2 + gid] = acc * (1.f / (float)PF);
  } else if (gid < LH2 + L) {
    int l = gid - LH2;
    double rad = (double)theta[l] * 0.017453292519943295;
    const float hw = 0.5f * (float)(WD - 1);
    float cx = (float)l * (float)((double)(WD - 1) / (double)(L - 1));
    float c0 = floorf(cx);
    float wc = cx - c0;
    int ia = (int)c0;
    float ok = (ia + 1 <= WD - 1) ? 1.f : 0.f;
    float4 a;
    a.x = (float)cos(rad) * hw;
    a.y = (float)sin(rad) * hw;
    a.z = wc * ok;                       // wB (0 when L==WD: cx = l exactly)
    a.w = __int_as_float(ia);
    ((float4*)(ws + OFF_ANG))[l] = a;
  }
}

// ---------------------------------------------------------------------------
// Filter v4: fp16 MFMA GEMM, SELF-CONTAINED s-tiles (R6 post-mortem: the
// cross-block sub-word stitching of boundary entries was the only schedule-
// dependent hazard; eliminated by computing ALL 512 s per block).
//   OUT[s,l] = sum_m H[s,m] x[m,l], H[s,m] = h2[s-m+512] (Toeplitz).
//   Block: 256 thr (4 waves), M=512 x N=32 (l-slab) x K=512. Grid 16 x 32.
//   Wave wv owns s in [wv*128, wv*128+128): 8 mf x 2 nf frags of
//   mfma_f32_16x16x32_f16; acc = 64 VGPR.
//   A (Toeplitz): 8 shift-copies of fp16-reversed h2 in LDS, PADDED stride
//   2064 B (2048 aliased all copies onto the same banks = 8-way conflict);
//   copy p = a0&7 at row offset a0&~7 holds h2rev[a0..a0+7] -> one aligned
//   ds_read_b128 per frag. a0 = 515 - s + k0 (verified: h2rev[515-s+k0+j]
//   = h2[s-(k0+j)+512]).
//   B: 32 cols x 32 k staged per kt (thread: col=t&31, k-quad=t>>5),
//   register-prefetched one kt ahead; Bl[c][k] ushort at c*40+k (80 B row,
//   2-way bank at worst).
//   Epilogue: acc -> outl[l][s] fp16 in LDS (32 x 520 ushorts = 33280 B,
//   reuses the A/B region after a barrier), then EVERY pk dword (lo=y[s],
//   hi=y[s+1]; s=511 hi=0) packed and stored by exactly one thread of this
//   block. No cross-block bytes anywhere; pk rows are 8 KB-aligned.
// ---------------------------------------------------------------------------
__global__ __launch_bounds__(256, 2) void filter_mfma(
    const float* __restrict__ x, const float* __restrict__ ws,
    unsigned char* __restrict__ pk) {
  __shared__ __align__(16) unsigned char smem[33280];
  // A-phase layout: [0,16512) h2 copies (8 x 1032 ushorts, 2064 B stride)
  //                 [16512,19072) Bl: 32 cols x 40 ushorts (80 B rows)
  // epilogue layout: [0,33280) outl: 32 l x 520 ushorts (1040 B rows)
  unsigned short* const h2cs = (unsigned short*)smem;
  unsigned char* const bls = smem + 16512;

  const int t = threadIdx.x;
  const int l0 = blockIdx.x << 5;            // l-slab [l0, l0+32)
  const int n = blockIdx.y;
  const int g = n >> 2, kimg = n & 3;
  const int lane = t & 63, wv = t >> 6;

  // h2cs[p][i] = fp16(h2rev[i+p]) = fp16(h2[1027-i-p]); OOB -> 0 (never read)
  for (int u = t; u < 8192; u += 256) {
    int p = u >> 10, i = u & 1023;
    int gi = 1027 - i - p;
    float v = (gi >= 0) ? ws[OFF_H2 + gi] : 0.f;
    h2cs[p * 1032 + i] = __builtin_bit_cast(unsigned short, (_Float16)v);
  }

  const float* __restrict__ xn = x + (size_t)n * (WD * WD);
  const int cc = t & 31, kq = t >> 5;        // B-stage: col, k-quad

  float pf[4];
  {                                          // prefetch kt = 0
    const float* xb = xn + (size_t)(kq * 4) * WD + l0 + cc;
#pragma unroll
    for (int r = 0; r < 4; ++r) pf[r] = xb[r * WD];
  }

  // a0 = aBase + kt*32 - mf*16; s = wv*128 + mf*16 + (lane&15),
  // k0 = kt*32 + (lane>>4)*8  ->  a0 = 515 - s + k0 in [4, 1019].
  const int aBase = 515 - (wv << 7) - (lane & 15) + ((lane >> 4) << 3);
  const int bcol = lane & 15, bq = lane >> 4;

  f32x4v acc[8][2];
#pragma unroll
  for (int i = 0; i < 8; ++i) {
    acc[i][0] = (f32x4v)0.f;
    acc[i][1] = (f32x4v)0.f;
  }

  for (int kt = 0; kt < 16; ++kt) {
    __syncthreads();                         // Bl free (prev frag reads done)
    *(unsigned*)(bls + cc * 80 + kq * 8) = pkbits(pf[0], pf[1]);
    *(unsigned*)(bls + cc * 80 + kq * 8 + 4) = pkbits(pf[2], pf[3]);
    __syncthreads();                         // Bl ready
    if (kt < 15) {                           // prefetch next kt
      const float* xb = xn + (size_t)((kt + 1) * 32 + kq * 4) * WD + l0 + cc;
#pragma unroll
      for (int r = 0; r < 4; ++r) pf[r] = xb[r * WD];
    }
    f16x8 bf[2];
#pragma unroll
    for (int nf = 0; nf < 2; ++nf)
      bf[nf] = *(const f16x8*)(bls + ((nf << 4) + bcol) * 80 + bq * 16);
    const int aK = aBase + (kt << 5);
#pragma unroll
    for (int mf = 0; mf < 8; ++mf) {
      int a0 = aK - (mf << 4);
      f16x8 af = *(const f16x8*)(smem + (a0 & 7) * 2064 + ((a0 & ~7) << 1));
      acc[mf][0] = __builtin_amdgcn_mfma_f32_16x16x32_f16(af, bf[0],
                                                          acc[mf][0], 0, 0, 0);
      acc[mf][1] = __builtin_amdgcn_mfma_f32_16x16x32_f16(af, bf[1],
                                                          acc[mf][1], 0, 0, 0);
    }
  }

  __syncthreads();                           // frag reads done; smem -> outl
  {                                          // phase 2: acc -> outl[l][s] fp16
    const int q = lane >> 4;
#pragma unroll
    for (int mf = 0; mf < 8; ++mf)
#pragma unroll
      for (int nf = 0; nf < 2; ++nf) {
        int l = (nf << 4) + (lane & 15);     // D col = lane&15 (N dim)
        int s0 = (wv << 7) + (mf << 4) + (q << 2);   // D row = q*4+v (M dim)
        f32x4v v = acc[mf][nf];
        uint2 pw;
        pw.x = pkbits(v[0], v[1]);
        pw.y = pkbits(v[2], v[3]);
        *(uint2*)(smem + l * 1040 + s0 * 2) = pw;
      }
  }
  __syncthreads();
  {                                          // phase 3: full-dword pk stores
    unsigned char* __restrict__ pg =
        pk + (size_t)g * (512u * 512u * 16u) + (size_t)kimg * 4;
    const int sl = t & 63, lw = t >> 6;
#pragma unroll
    for (int li = 0; li < 8; ++li) {
      int l = (lw << 3) + li;
      const unsigned short* row = (const unsigned short*)(smem + l * 1040);
      unsigned char* rowp = pg + (size_t)(l0 + l) * (512 * 16);
#pragma unroll
      for (int sh = 0; sh < 8; ++sh) {
        int s = (sh << 6) + sl;
        unsigned lo = row[s];
        unsigned hi = (s < 511) ? (unsigned)row[s + 1] : 0u;   // entry 511 hi=0
        *(unsigned*)(rowp + (size_t)s * 16) = lo | (hi << 16);
      }
    }
  }
}

// ---------------------------------------------------------------------------
// Backprojection v6 (R2-exact, best measured 433.3 us): 1024-thread blocks,
// 64x64 px x 4 imgs, TWO angles per LDS round, ONE barrier per 2 angles,
// ds_write staging. R3/R4/R5: gload_lds neutral, barrier-free -22%,
// barrier-halving -6% -> this structure's plateau; keep verbatim.
// R1 lesson: vector-memory gathers are line-serial (~26cy) — LDS only.
// ---------------------------------------------------------------------------
__device__ __forceinline__ uint4 blend4(uint4 a, uint4 b, float wA, float wB) {
  unsigned r[4];
  const unsigned* pa = &a.x; const unsigned* pb = &b.x;
#pragma unroll
  for (int i = 0; i < 4; ++i) {
    half2_t ha = __builtin_bit_cast(half2_t, pa[i]);
    half2_t hb = __builtin_bit_cast(half2_t, pb[i]);
    r[i] = pkbits(fmaf((float)ha.x, wA, (float)hb.x * wB),
                  fmaf((float)ha.y, wA, (float)hb.y * wB));
  }
  return make_uint4(r[0], r[1], r[2], r[3]);
}

__device__ __forceinline__ void loadrow(const unsigned char* gb, float4 a, int s,
                                        uint4& v) {
  int ia = __float_as_int(a.w);
  v = *(const uint4*)(gb + (size_t)ia * (512 * 16) + (size_t)s * 16);
  float wB = a.z;
  if (wB != 0.f) {                       // generic angle interp (never taken, L==WD)
    int ib = ia + 1 < 511 ? ia + 1 : 511;
    uint4 u = *(const uint4*)(gb + (size_t)ib * (512 * 16) + (size_t)s * 16);
    v = blend4(v, u, 1.f - wB, wB);
  }
}

__device__ __forceinline__ void accum_angle(const uint4* __restrict__ br,
                                            float4 a, float tiv,
                                            const float* __restrict__ tjv,
                                            float hw, float acc[4][4]) {
  const float chw = a.x, shw = a.y;
  float bi = fmaf(tiv, -shw, hw);
#pragma unroll
  for (int dj = 0; dj < 4; ++dj) {
    float ry = fmaf(tjv[dj], chw, bi);
    int idx = (int)ry;                   // trunc; OOB lands in zero guards
    float w1 = ry - (float)idx;
    half2_t wpk = pkh(1.f - w1, w1);
    uint4 q = br[idx + GOFF];            // one ds_read_b128 serves 4 images
    acc[dj][0] = dot2f(q.x, wpk, acc[dj][0]);
    acc[dj][1] = dot2f(q.y, wpk, acc[dj][1]);
    acc[dj][2] = dot2f(q.z, wpk, acc[dj][2]);
    acc[dj][3] = dot2f(q.w, wpk, acc[dj][3]);
  }
}

__global__ __launch_bounds__(1024, 8) void backproj_kernel(
    const float* __restrict__ ws, const unsigned char* __restrict__ pk,
    float* __restrict__ out, int L) {
  __shared__ __align__(16) uint4 buf[2][2][GSLOTS];   // [round parity][angle][slot]
  const int t = threadIdx.x;
  const int tx = t & 15, ty = t >> 4;        // ty: 0..63 (full i of tile)
  const int j0 = (blockIdx.x & 7) << 6;
  const int i0 = (blockIdx.x >> 3) << 6;
  const int g = blockIdx.y;
  const int n0 = g << 2;

  const float tiv = t2(i0 + ty);
  float tjv[4];
#pragma unroll
  for (int a = 0; a < 4; ++a) tjv[a] = t2(j0 + tx + 16 * a);

  // Corner-tile skip: entire 64x64 tile outside the circle -> zeros, no compute.
  {
    float il = t2(i0), ih = t2(i0 + 63);
    float jl = t2(j0), jh = t2(j0 + 63);
    float mi = (il <= 0.f && ih >= 0.f) ? 0.f : fminf(fabsf(il), fabsf(ih));
    float mj = (jl <= 0.f && jh >= 0.f) ? 0.f : fminf(fabsf(jl), fabsf(jh));
    if (mi * mi + mj * mj > 1.f) {
#pragma unroll
      for (int k = 0; k < 4; ++k) {
        float* ob = out + (size_t)(n0 + k) * WD * WD + (size_t)(i0 + ty) * WD;
#pragma unroll
        for (int dj = 0; dj < 4; ++dj) ob[j0 + tx + 16 * dj] = 0.f;
      }
      return;
    }
  }

  const float4* __restrict__ angp = (const float4*)(ws + OFF_ANG);
  const unsigned char* gb = pk + (size_t)g * (512 * 512 * 16);

  for (int s = t; s < 2 * 2 * GSLOTS; s += 1024)
    ((uint4*)buf)[s] = make_uint4(0u, 0u, 0u, 0u);
  __syncthreads();                       // guards visible before first staging

  const float hw = 0.5f * (float)(WD - 1);
  float acc[4][4] = {};                  // [dj][img]

  const int sA = t & 511;                // staged slot
  const int p = t >> 9;                  // which of the round's 2 angles we stage

  float4 aA = angp[0];
  float4 aB = angp[L > 1 ? 1 : 0];
  uint4 v;
  loadrow(gb, p ? aB : aA, sA, v);

  const int rounds = (L + 1) >> 1;
  for (int r = 0; r < rounds; ++r) {
    const int rp = r & 1;
    buf[rp][p][GOFF + sA] = v;           // 1 ds_write_b128, conflict-free
    int na = 2 * r + 2, nb = 2 * r + 3;
    float4 aA2 = angp[na < L ? na : L - 1];
    float4 aB2 = angp[nb < L ? nb : L - 1];
    if (r + 1 < rounds) loadrow(gb, p ? aB2 : aA2, sA, v);   // overlap compute
    __syncthreads();                     // ONE barrier per 2 angles

    accum_angle(&buf[rp][0][0], aA, tiv, tjv, hw, acc);
    if (2 * r + 1 < L)
      accum_angle(&buf[rp][1][0], aB, tiv, tjv, hw, acc);
    aA = aA2; aB = aB2;
  }

  const float scale = (float)(3.14159265358979323846 / (2.0 * (double)L));
#pragma unroll
  for (int k = 0; k < 4; ++k) {
    float* ob = out + (size_t)(n0 + k) * WD * WD + (size_t)(i0 + ty) * WD;
#pragma unroll
    for (int dj = 0; dj < 4; ++dj) {
      float rr = tiv * tiv + tjv[dj] * tjv[dj];
      ob[j0 + tx + 16 * dj] = (rr <= 1.f) ? acc[dj][k] * scale : 0.f;
    }
  }
}

extern "C" void kernel_launch(void* const* d_in, const int* in_sizes, int n_in,
                              void* d_out, int out_size, void* d_ws, size_t ws_size,
                              hipStream_t stream) {
  const float* x = (const float*)d_in[0];
  const float* theta = (const float*)d_in[1];
  float* out = (float*)d_out;
  float* ws = (float*)d_ws;
  int L = in_sizes[1];                       // 512
  int NC = in_sizes[0] / (WD * WD);          // 32
  unsigned char* pk = (unsigned char*)(ws + OFF_PK);

  int nset = LH2 + L;
  hipLaunchKernelGGL(setup_kernel, dim3((nset + 255) / 256), dim3(256), 0, stream,
                     theta, ws, L);
  hipLaunchKernelGGL(filter_mfma, dim3(16, NC), dim3(256), 0, stream,
                     x, ws, pk);
  hipLaunchKernelGGL(backproj_kernel, dim3(64, NC / 4), dim3(1024), 0, stream,
                     ws, pk, out, L);
}

// Round 8
// 494.580 us; speedup vs baseline: 1.3145x; 1.0057x over previous
//
#include <hip/hip_runtime.h>
#include <math.h>

// Problem constants (setup_inputs: N=32, C=1, W=512, L=512)
#define WD 512          // image / detector width
#define PF 1024         // FFT pad length
#define LH2 1028        // shifted ramp-kernel table length

// Workspace layout (float offsets). ws bytes: 16 KB + 33.55 MB table.
#define OFF_H2 0        // 1028 floats
#define OFF_ANG 2048    // 512 x float4 (chw, shw, wB, iA-bits)
#define OFF_PK 4096     // packed fp16 sinogram: [g][l][s] uint4 (4 imgs x (y[s],y[s+1]))

#define GOFF 107        // LDS slot = detector_index + GOFF (guards absorb out-of-circle idx)
#define GSLOTS 726      // covers idx in [-107, 618]

typedef __fp16 half2_t __attribute__((ext_vector_type(2)));
typedef _Float16 f16x8 __attribute__((ext_vector_type(8)));
typedef float f32x4v __attribute__((ext_vector_type(4)));

__device__ __forceinline__ half2_t pkh(float a, float b) {
  return __builtin_amdgcn_cvt_pkrtz(a, b);   // v_cvt_pkrtz_f16_f32
}
__device__ __forceinline__ unsigned pkbits(float a, float b) {
  return __builtin_bit_cast(unsigned, pkh(a, b));
}
__device__ __forceinline__ float dot2f(unsigned tapbits, half2_t w, float c) {
  half2_t tp = __builtin_bit_cast(half2_t, tapbits);
  return __builtin_amdgcn_fdot2(tp, w, c, false);   // v_dot2_f32_f16
}

__device__ __forceinline__ float t2(int p) {
  return (float)(-1.0 + 2.0 * (double)p / (double)(WD - 1));
}

// ---------------------------------------------------------------------------
// Setup: h2[i] = h[(i-512) & 1023] via v_cos (arg in REVOLUTIONS). UNCHANGED.
// ---------------------------------------------------------------------------
__global__ void setup_kernel(const float* __restrict__ theta,
                             float* __restrict__ ws, int L) {
  int gid = blockIdx.x * blockDim.x + threadIdx.x;
  if (gid < LH2) {
    int dd = gid - (PF / 2);
    if (dd < 0) dd = -dd;
    float acc = 0.f;
    for (int k = 0; k < PF; ++k) {
      int kk = (k <= PF / 2) ? k : (PF - k);
      float filt = 2.f * (float)kk * (1.f / (float)PF);
      int m = (k * dd) & (PF - 1);            // phase in [0,1) revolutions
#if __has_builtin(__builtin_amdgcn_cosf)
      float cv = __builtin_amdgcn_cosf((float)m * (1.f / (float)PF));
#else
      float cv = cosf((float)m * (6.28318530717958647692f / (float)PF));
#endif
      acc = fmaf(filt, cv, acc);
    }
    ws[OFF_H2 + gid] = acc * (1.f / (float)PF);
  } else if (gid < LH2 + L) {
    int l = gid - LH2;
    double rad = (double)theta[l] * 0.017453292519943295;
    const float hw = 0.5f * (float)(WD - 1);
    float cx = (float)l * (float)((double)(WD - 1) / (double)(L - 1));
    float c0 = floorf(cx);
    float wc = cx - c0;
    int ia = (int)c0;
    float ok = (ia + 1 <= WD - 1) ? 1.f : 0.f;
    float4 a;
    a.x = (float)cos(rad) * hw;
    a.y = (float)sin(rad) * hw;
    a.z = wc * ok;                       // wB (0 when L==WD: cx = l exactly)
    a.w = __int_as_float(ia);
    ((float4*)(ws + OFF_ANG))[l] = a;
  }
}

// ---------------------------------------------------------------------------
// Filter v5: fp16 MFMA GEMM, self-contained s-tiles (correctness structure
// of v4 preserved byte-for-byte in indexing/numerics — R7 passed with
// absmax bit-identical). Changes vs v4 are pipeline-only:
//  - Bl DOUBLE-BUFFERED (2 x 2560 B): write Bl[kt&1] -> ONE barrier -> read.
//    The kt+1 barrier orders kt+2's buffer reuse (lgkmcnt drains at barrier),
//    so one barrier per kt is race-free. (v4 paid two barriers per kt.)
//  - kt loop FULLY UNROLLED (16x): pf[] and Bl indices become compile-time
//    (rule: runtime-indexed reg arrays spill), and the scheduler can hoist
//    the next x-tile's global loads ~2 iterations (~800 cy) ahead, covering
//    cold-HBM latency that the v4 1-deep prefetch (~300 cy window) exposed.
//   GEMM: OUT[s,l] = sum_m H[s,m] x[m,l], H[s,m] = h2[s-m+512] (Toeplitz).
//   Block: 256 thr (4 waves), M=512 x N=32 (l-slab) x K=512. Grid 16 x 32.
//   A: 8 shift-copies of fp16-reversed h2 in LDS (stride 2064 B, bank-clean);
//   copy p = a0&7 at row offset a0&~7 holds h2rev[a0..a0+7] -> one aligned
//   ds_read_b128 per frag; a0 = 515 - s + k0.
//   Epilogue: acc -> outl[l][s] fp16 in LDS, then every pk dword assembled
//   and stored by exactly one thread of this block (no cross-block bytes).
// ---------------------------------------------------------------------------
__global__ __launch_bounds__(256, 2) void filter_mfma(
    const float* __restrict__ x, const float* __restrict__ ws,
    unsigned char* __restrict__ pk) {
  __shared__ __align__(16) unsigned char smem[33280];
  // phase-1 layout: [0,16512) h2 copies (8 x 1032 ushorts, 2064 B stride)
  //                 [16512,21632) Bl[2]: 2 x (32 cols x 40 ushorts, 80 B rows)
  // epilogue layout: [0,33280) outl: 32 l x 520 ushorts (1040 B rows)
  unsigned short* const h2cs = (unsigned short*)smem;
  unsigned char* const bls = smem + 16512;

  const int t = threadIdx.x;
  const int l0 = blockIdx.x << 5;            // l-slab [l0, l0+32)
  const int n = blockIdx.y;
  const int g = n >> 2, kimg = n & 3;
  const int lane = t & 63, wv = t >> 6;

  // h2cs[p][i] = fp16(h2rev[i+p]) = fp16(h2[1027-i-p]); OOB -> 0 (never read)
  for (int u = t; u < 8192; u += 256) {
    int p = u >> 10, i = u & 1023;
    int gi = 1027 - i - p;
    float v = (gi >= 0) ? ws[OFF_H2 + gi] : 0.f;
    h2cs[p * 1032 + i] = __builtin_bit_cast(unsigned short, (_Float16)v);
  }

  const float* __restrict__ xn = x + (size_t)n * (WD * WD);
  const int cc = t & 31, kq = t >> 5;        // B-stage: col, k-quad

  // a0 = aBase + kt*32 - mf*16; s = wv*128 + mf*16 + (lane&15),
  // k0 = kt*32 + (lane>>4)*8  ->  a0 = 515 - s + k0 in [4, 1019].
  const int aBase = 515 - (wv << 7) - (lane & 15) + ((lane >> 4) << 3);
  const int bcol = lane & 15, bq = lane >> 4;

  f32x4v acc[8][2];
#pragma unroll
  for (int i = 0; i < 8; ++i) {
    acc[i][0] = (f32x4v)0.f;
    acc[i][1] = (f32x4v)0.f;
  }

  float pf[2][4];
  {                                          // preload kt = 0 tile
    const float* xb = xn + (size_t)(kq * 4) * WD + l0 + cc;
#pragma unroll
    for (int r = 0; r < 4; ++r) pf[0][r] = xb[r * WD];
  }

#pragma unroll
  for (int kt = 0; kt < 16; ++kt) {
    const int cur = kt & 1;
    if (kt < 15) {                           // issue next tile's loads early
      const float* xb = xn + (size_t)((kt + 1) * 32 + kq * 4) * WD + l0 + cc;
#pragma unroll
      for (int r = 0; r < 4; ++r) pf[cur ^ 1][r] = xb[r * WD];
    }
    unsigned char* bl = bls + cur * 2560;
    *(unsigned*)(bl + cc * 80 + kq * 8) = pkbits(pf[cur][0], pf[cur][1]);
    *(unsigned*)(bl + cc * 80 + kq * 8 + 4) = pkbits(pf[cur][2], pf[cur][3]);
    __syncthreads();                         // Bl[cur] ready (ONE barrier/kt)
    f16x8 bf[2];
#pragma unroll
    for (int nf = 0; nf < 2; ++nf)
      bf[nf] = *(const f16x8*)(bl + ((nf << 4) + bcol) * 80 + bq * 16);
    const int aK = aBase + (kt << 5);
#pragma unroll
    for (int mf = 0; mf < 8; ++mf) {
      int a0 = aK - (mf << 4);
      f16x8 af = *(const f16x8*)(smem + (a0 & 7) * 2064 + ((a0 & ~7) << 1));
      acc[mf][0] = __builtin_amdgcn_mfma_f32_16x16x32_f16(af, bf[0],
                                                          acc[mf][0], 0, 0, 0);
      acc[mf][1] = __builtin_amdgcn_mfma_f32_16x16x32_f16(af, bf[1],
                                                          acc[mf][1], 0, 0, 0);
    }
  }

  __syncthreads();                           // frag reads done; smem -> outl
  {                                          // phase 2: acc -> outl[l][s] fp16
    const int q = lane >> 4;
#pragma unroll
    for (int mf = 0; mf < 8; ++mf)
#pragma unroll
      for (int nf = 0; nf < 2; ++nf) {
        int l = (nf << 4) + (lane & 15);     // D col = lane&15 (N dim)
        int s0 = (wv << 7) + (mf << 4) + (q << 2);   // D row = q*4+v (M dim)
        f32x4v v = acc[mf][nf];
        uint2 pw;
        pw.x = pkbits(v[0], v[1]);
        pw.y = pkbits(v[2], v[3]);
        *(uint2*)(smem + l * 1040 + s0 * 2) = pw;
      }
  }
  __syncthreads();
  {                                          // phase 3: full-dword pk stores
    unsigned char* __restrict__ pg =
        pk + (size_t)g * (512u * 512u * 16u) + (size_t)kimg * 4;
    const int sl = t & 63, lw = t >> 6;
#pragma unroll
    for (int li = 0; li < 8; ++li) {
      int l = (lw << 3) + li;
      const unsigned short* row = (const unsigned short*)(smem + l * 1040);
      unsigned char* rowp = pg + (size_t)(l0 + l) * (512 * 16);
#pragma unroll
      for (int sh = 0; sh < 8; ++sh) {
        int s = (sh << 6) + sl;
        unsigned lo = row[s];
        unsigned hi = (s < 511) ? (unsigned)row[s + 1] : 0u;   // entry 511 hi=0
        *(unsigned*)(rowp + (size_t)s * 16) = lo | (hi << 16);
      }
    }
  }
}

// ---------------------------------------------------------------------------
// Backprojection v6 (R2-exact, best measured 426-433 us): 1024-thread blocks,
// 64x64 px x 4 imgs, TWO angles per LDS round, ONE barrier per 2 angles,
// ds_write staging. R3/R4/R5: gload_lds neutral, barrier-free -22%,
// barrier-halving -6% -> this structure's plateau; keep verbatim.
// R1 lesson: vector-memory gathers are line-serial (~26cy) — LDS only.
// ---------------------------------------------------------------------------
__device__ __forceinline__ uint4 blend4(uint4 a, uint4 b, float wA, float wB) {
  unsigned r[4];
  const unsigned* pa = &a.x; const unsigned* pb = &b.x;
#pragma unroll
  for (int i = 0; i < 4; ++i) {
    half2_t ha = __builtin_bit_cast(half2_t, pa[i]);
    half2_t hb = __builtin_bit_cast(half2_t, pb[i]);
    r[i] = pkbits(fmaf((float)ha.x, wA, (float)hb.x * wB),
                  fmaf((float)ha.y, wA, (float)hb.y * wB));
  }
  return make_uint4(r[0], r[1], r[2], r[3]);
}

__device__ __forceinline__ void loadrow(const unsigned char* gb, float4 a, int s,
                                        uint4& v) {
  int ia = __float_as_int(a.w);
  v = *(const uint4*)(gb + (size_t)ia * (512 * 16) + (size_t)s * 16);
  float wB = a.z;
  if (wB != 0.f) {                       // generic angle interp (never taken, L==WD)
    int ib = ia + 1 < 511 ? ia + 1 : 511;
    uint4 u = *(const uint4*)(gb + (size_t)ib * (512 * 16) + (size_t)s * 16);
    v = blend4(v, u, 1.f - wB, wB);
  }
}

__device__ __forceinline__ void accum_angle(const uint4* __restrict__ br,
                                            float4 a, float tiv,
                                            const float* __restrict__ tjv,
                                            float hw, float acc[4][4]) {
  const float chw = a.x, shw = a.y;
  float bi = fmaf(tiv, -shw, hw);
#pragma unroll
  for (int dj = 0; dj < 4; ++dj) {
    float ry = fmaf(tjv[dj], chw, bi);
    int idx = (int)ry;                   // trunc; OOB lands in zero guards
    float w1 = ry - (float)idx;
    half2_t wpk = pkh(1.f - w1, w1);
    uint4 q = br[idx + GOFF];            // one ds_read_b128 serves 4 images
    acc[dj][0] = dot2f(q.x, wpk, acc[dj][0]);
    acc[dj][1] = dot2f(q.y, wpk, acc[dj][1]);
    acc[dj][2] = dot2f(q.z, wpk, acc[dj][2]);
    acc[dj][3] = dot2f(q.w, wpk, acc[dj][3]);
  }
}

__global__ __launch_bounds__(1024, 8) void backproj_kernel(
    const float* __restrict__ ws, const unsigned char* __restrict__ pk,
    float* __restrict__ out, int L) {
  __shared__ __align__(16) uint4 buf[2][2][GSLOTS];   // [round parity][angle][slot]
  const int t = threadIdx.x;
  const int tx = t & 15, ty = t >> 4;        // ty: 0..63 (full i of tile)
  const int j0 = (blockIdx.x & 7) << 6;
  const int i0 = (blockIdx.x >> 3) << 6;
  const int g = blockIdx.y;
  const int n0 = g << 2;

  const float tiv = t2(i0 + ty);
  float tjv[4];
#pragma unroll
  for (int a = 0; a < 4; ++a) tjv[a] = t2(j0 + tx + 16 * a);

  // Corner-tile skip: entire 64x64 tile outside the circle -> zeros, no compute.
  {
    float il = t2(i0), ih = t2(i0 + 63);
    float jl = t2(j0), jh = t2(j0 + 63);
    float mi = (il <= 0.f && ih >= 0.f) ? 0.f : fminf(fabsf(il), fabsf(ih));
    float mj = (jl <= 0.f && jh >= 0.f) ? 0.f : fminf(fabsf(jl), fabsf(jh));
    if (mi * mi + mj * mj > 1.f) {
#pragma unroll
      for (int k = 0; k < 4; ++k) {
        float* ob = out + (size_t)(n0 + k) * WD * WD + (size_t)(i0 + ty) * WD;
#pragma unroll
        for (int dj = 0; dj < 4; ++dj) ob[j0 + tx + 16 * dj] = 0.f;
      }
      return;
    }
  }

  const float4* __restrict__ angp = (const float4*)(ws + OFF_ANG);
  const unsigned char* gb = pk + (size_t)g * (512 * 512 * 16);

  for (int s = t; s < 2 * 2 * GSLOTS; s += 1024)
    ((uint4*)buf)[s] = make_uint4(0u, 0u, 0u, 0u);
  __syncthreads();                       // guards visible before first staging

  const float hw = 0.5f * (float)(WD - 1);
  float acc[4][4] = {};                  // [dj][img]

  const int sA = t & 511;                // staged slot
  const int p = t >> 9;                  // which of the round's 2 angles we stage

  float4 aA = angp[0];
  float4 aB = angp[L > 1 ? 1 : 0];
  uint4 v;
  loadrow(gb, p ? aB : aA, sA, v);

  const int rounds = (L + 1) >> 1;
  for (int r = 0; r < rounds; ++r) {
    const int rp = r & 1;
    buf[rp][p][GOFF + sA] = v;           // 1 ds_write_b128, conflict-free
    int na = 2 * r + 2, nb = 2 * r + 3;
    float4 aA2 = angp[na < L ? na : L - 1];
    float4 aB2 = angp[nb < L ? nb : L - 1];
    if (r + 1 < rounds) loadrow(gb, p ? aB2 : aA2, sA, v);   // overlap compute
    __syncthreads();                     // ONE barrier per 2 angles

    accum_angle(&buf[rp][0][0], aA, tiv, tjv, hw, acc);
    if (2 * r + 1 < L)
      accum_angle(&buf[rp][1][0], aB, tiv, tjv, hw, acc);
    aA = aA2; aB = aB2;
  }

  const float scale = (float)(3.14159265358979323846 / (2.0 * (double)L));
#pragma unroll
  for (int k = 0; k < 4; ++k) {
    float* ob = out + (size_t)(n0 + k) * WD * WD + (size_t)(i0 + ty) * WD;
#pragma unroll
    for (int dj = 0; dj < 4; ++dj) {
      float rr = tiv * tiv + tjv[dj] * tjv[dj];
      ob[j0 + tx + 16 * dj] = (rr <= 1.f) ? acc[dj][k] * scale : 0.f;
    }
  }
}

extern "C" void kernel_launch(void* const* d_in, const int* in_sizes, int n_in,
                              void* d_out, int out_size, void* d_ws, size_t ws_size,
                              hipStream_t stream) {
  const float* x = (const float*)d_in[0];
  const float* theta = (const float*)d_in[1];
  float* out = (float*)d_out;
  float* ws = (float*)d_ws;
  int L = in_sizes[1];                       // 512
  int NC = in_sizes[0] / (WD * WD);          // 32
  unsigned char* pk = (unsigned char*)(ws + OFF_PK);

  int nset = LH2 + L;
  hipLaunchKernelGGL(setup_kernel, dim3((nset + 255) / 256), dim3(256), 0, stream,
                     theta, ws, L);
  hipLaunchKernelGGL(filter_mfma, dim3(16, NC), dim3(256), 0, stream,
                     x, ws, pk);
  hipLaunchKernelGGL(backproj_kernel, dim3(64, NC / 4), dim3(1024), 0, stream,
                     ws, pk, out, L);
}